// Round 1
// 682.803 us; speedup vs baseline: 1.0140x; 1.0140x over previous
//
#include <hip/hip_runtime.h>
#include <stdint.h>

// RetentionPolicy forward (training) — round 4.
// ONE ROW PER WAVE (4 rows / 256-thr block, grid 4096). No __syncthreads,
// no atomics, no inter-wave traffic: each wave owns a private 256-slot LDS
// candidate buffer and a private 128-slot index buffer.
// Stream pass: coalesced float4 loads, per-64-group ballot compaction with a
// wave-uniform SCALAR running base (s_bcnt1+s_add chain instead of the old
// lane0-atomicAdd+shfl broadcast round-trip). Survivors (x >= -2.0, ~187/row)
// stored as (okey32<<32)|idx.
// Tail (same wave, all waves busy):
//   - candidates -> registers (4/lane)
//   - T from sign-bit ballot count of candidates
//   - T-th largest via 32-step ballot bisection (VALU/SALU only)
//   - exact index tie-break via 13-step idx bisect (rare)
//   - compact selected indices, 128-wide 2/lane shuffle bitonic ascending
//   - emit bs/cls/mask
// Fallbacks (stats-never, correctness only): M<20 or M>256 -> wave-local
// exact 45-bit composite bisect over the row re-read from global.

#define BSZ   16384
#define KDIM  8192
#define MAXC  100
#define TMIN  20
#define CAP   256
#define RPB   4      // rows per block = waves per block

__device__ __forceinline__ uint32_t okey(float x) {
  uint32_t b = __float_as_uint(x);
  return (b & 0x80000000u) ? ~b : (b | 0x80000000u);   // monotone float->uint
}

__global__ __launch_bounds__(256, 8)
void retention_kernel(const float* __restrict__ in,
                      int* __restrict__ out_bs,
                      int* __restrict__ out_cls,
                      int* __restrict__ out_mask) {
  const int tid  = threadIdx.x;
  const int wv   = tid >> 6;
  const int lane = tid & 63;
  const int row  = blockIdx.x * RPB + wv;

  __shared__ unsigned long long buf_s[RPB][CAP];
  __shared__ int sidx_s[RPB][128];
  unsigned long long* buf = buf_s[wv];
  int* sidx = sidx_s[wv];

  const float4* src = (const float4*)(in + (size_t)row * KDIM);

  // ---- streaming filter: ballot compaction, scalar running base ----
  unsigned base = 0;
  #pragma unroll
  for (int b = 0; b < 8; ++b) {
    float4 f[4];
    #pragma unroll
    for (int j = 0; j < 4; ++j) f[j] = src[lane + 64 * (4 * b + j)];
    #pragma unroll
    for (int j = 0; j < 4; ++j) {
      float v[4] = {f[j].x, f[j].y, f[j].z, f[j].w};
      #pragma unroll
      for (int m = 0; m < 4; ++m) {
        float x = v[m];
        bool q = (x >= -2.0f);
        unsigned long long mk = __ballot(q);
        if (q) {
          unsigned p = base + (unsigned)__popcll(mk & ((1ull << lane) - 1ull));
          if (p < CAP) {
            int idx = 4 * lane + 256 * (4 * b + j) + m;
            buf[p] = ((unsigned long long)okey(x) << 32) | (unsigned)idx;
          }
        }
        base += (unsigned)__popcll(mk);
      }
    }
  }
  __threadfence_block();            // wave-synchronous LDS write->read

  int M = (int)base;
  int T = -1;                       // set by fallback if taken

  // ---- fallback: exact composite bisect over global (never taken) ----
  if (M < TMIN || M > CAP) {
    const float* rp = in + (size_t)row * KDIM;
    int cp = 0;
    for (int e = lane; e < KDIM; e += 64) cp += (rp[e] >= 0.0f);
    #pragma unroll
    for (int off = 32; off; off >>= 1) cp += __shfl_down(cp, off, 64);
    cp = __shfl(cp, 0, 64);
    T = min(max(cp, TMIN), MAXC);

    unsigned long long lo = 0, hi = 1ull << 45, t = 0;
    int c;
    while (true) {                  // distinct composites => terminates
      unsigned long long mid = lo + ((hi - lo) >> 1);
      c = 0;
      for (int e = lane; e < KDIM; e += 64) {
        unsigned long long comp =
            ((unsigned long long)okey(rp[e]) << 13) | (unsigned)(8191 - e);
        c += (comp > mid) ? 1 : 0;
      }
      #pragma unroll
      for (int off = 32; off; off >>= 1) c += __shfl_down(c, off, 64);
      c = __shfl(c, 0, 64);
      if (c >= T && c <= CAP) { t = mid; break; }
      if (c < T) hi = mid; else lo = mid;
    }
    unsigned fb = 0;                // wave-local refill, no atomics
    for (int e = lane; e < KDIM; e += 64) {
      unsigned long long comp =
          ((unsigned long long)okey(rp[e]) << 13) | (unsigned)(8191 - e);
      bool q = comp > t;
      unsigned long long mk = __ballot(q);
      if (q) buf[fb + (unsigned)__popcll(mk & ((1ull << lane) - 1ull))] =
                 ((unsigned long long)okey(rp[e]) << 32) | (unsigned)e;
      fb += (unsigned)__popcll(mk);
    }
    M = c;
    __threadfence_block();
  }

  // ---- candidates -> registers (pad: val=0, ix=0x7FFF never selected) ----
  uint32_t val[4]; int ix[4];
  #pragma unroll
  for (int r = 0; r < 4; ++r) {
    int s = r * 64 + lane;
    unsigned long long c = (s < M) ? buf[s] : 0x0000000000007FFFull;
    val[r] = (uint32_t)(c >> 32);
    ix[r]  = (int)(c & 0xFFFFFFFFull);
  }

  if (T < 0) {                      // main path: positives from candidates
    int cp = 0;
    #pragma unroll
    for (int r = 0; r < 4; ++r)
      cp += (int)__popcll(__ballot((val[r] & 0x80000000u) != 0u));
    T = min(max(cp, TMIN), MAXC);
  }

  // ---- T-th largest value: 32-step ballot bisect (VALU/SALU only) ----
  uint32_t blo = 0, bhi = 0xFFFFFFFFu;
  while (blo < bhi) {
    uint32_t mid = blo + ((bhi - blo) >> 1);
    int c = 0;
    #pragma unroll
    for (int r = 0; r < 4; ++r) c += (int)__popcll(__ballot(val[r] > mid));
    if (c < T) bhi = mid; else blo = mid + 1;
  }
  const uint32_t vT = blo;          // smallest w with #(val>w) < T
  int c_gt = 0, c_eq = 0;
  #pragma unroll
  for (int r = 0; r < 4; ++r) {
    c_gt += (int)__popcll(__ballot(val[r] > vT));
    c_eq += (int)__popcll(__ballot(val[r] == vT));
  }
  const int need = T - c_gt;        // >= 1, <= c_eq
  int dcut = 0x3FFF;                // select ties with idx <= dcut (excl. pads)
  if (c_eq != need) {               // rare: float-equal tie straddles rank T
    int lo2 = 0, hi2 = 0x7FFF;
    while (lo2 < hi2) {
      int mid = (lo2 + hi2) >> 1;
      int g = 0;
      #pragma unroll
      for (int r = 0; r < 4; ++r)
        g += (int)__popcll(__ballot(val[r] == vT && ix[r] <= mid));
      if (g >= need) hi2 = mid; else lo2 = mid + 1;
    }
    dcut = lo2;                     // exactly `need` ties have idx <= dcut
  }

  // ---- compact exactly-T selected indices into LDS ----
  unsigned sb = 0;
  #pragma unroll
  for (int r = 0; r < 4; ++r) {
    bool sel = (val[r] > vT) || (val[r] == vT && ix[r] <= dcut);
    unsigned long long mk = __ballot(sel);
    if (sel) sidx[sb + (unsigned)__popcll(mk & ((1ull << lane) - 1ull))] = ix[r];
    sb += (unsigned)__popcll(mk);
  }
  __threadfence_block();            // wave-synchronous LDS write->read

  // ---- ascending sort of 128 (2/lane), wave-synchronous shuffle bitonic ----
  int a0 = (lane < T)      ? sidx[lane]      : 0x7FFFFFFF;
  int a1 = (64 + lane < T) ? sidx[64 + lane] : 0x7FFFFFFF;
  #pragma unroll
  for (int k = 2; k <= 128; k <<= 1) {
    for (int j = k >> 1; j; j >>= 1) {
      if (j == 64) {                // only at k=128; both halves ascending
        int mn = min(a0, a1), mx = max(a0, a1);
        a0 = mn; a1 = mx;
      } else {
        int o0 = __shfl_xor(a0, j, 64);
        int o1 = __shfl_xor(a1, j, 64);
        const bool lower = (lane & j) == 0;
        const bool asc0 = ((lane & k) == 0);
        const bool asc1 = (((64 + lane) & k) == 0);
        a0 = (lower != asc0) ? max(a0, o0) : min(a0, o0);
        a1 = (lower != asc1) ? max(a1, o1) : min(a1, o1);
      }
    }
  }

  // ---- emit ----
  const size_t o = (size_t)row * MAXC;
  if (lane < MAXC) {
    const bool vv = lane < T;
    out_bs[o + lane]   = vv ? row : -1;
    out_cls[o + lane]  = vv ? a0 : -1;
    out_mask[o + lane] = vv ? 1 : 0;
  }
  const int p = 64 + lane;
  if (p < MAXC) {
    const bool vv = p < T;
    out_bs[o + p]   = vv ? row : -1;
    out_cls[o + p]  = vv ? a1 : -1;
    out_mask[o + p] = vv ? 1 : 0;
  }
}

extern "C" void kernel_launch(void* const* d_in, const int* in_sizes, int n_in,
                              void* d_out, int out_size, void* d_ws, size_t ws_size,
                              hipStream_t stream) {
  const float* logits = (const float*)d_in[0];
  int* out = (int*)d_out;
  int* out_bs   = out;
  int* out_cls  = out + (size_t)BSZ * MAXC;
  int* out_mask = out + 2 * (size_t)BSZ * MAXC;
  retention_kernel<<<BSZ / RPB, 256, 0, stream>>>(logits, out_bs, out_cls, out_mask);
}